// Round 5
// baseline (433.215 us; speedup 1.0000x reference)
//
#include <hip/hip_runtime.h>
#include <hip/hip_fp16.h>
#include <hip/hip_cooperative_groups.h>
#include <cstdint>

namespace cg = cooperative_groups;

// ---------------------------------------------------------------------------
// SingleDeformConv on MI355X (gfx950)
// data (8,64,128,128) f32; w (64,64,3,3); b (64); w_off (18,64,3,3); b_off(18);
// w_mod (9,64,3,3); b_mod (9).  out = relu(deform_conv(...)) (8,64,128,128) f32
//
// R15 -> R16: ONE cooperative mega-kernel. Ledger across R12-R15: deform
// 45.3us, bucket-without-conv27 = 87.4us (reproduced 86.5), conv27 rewrite
// moved total by only ~2us => the remaining ~115us is dominated by
// per-dispatch gaps + fixed overhead, not kernel work (prep structural cost
// ~10us for 50MB). Fix: merge prep + conv27 + deform into one
// hipLaunchCooperativeKernel dispatch (1024 blocks x 256 thr, 4 blocks/CU
// co-resident; LDS 32256B union; grid-stride loops; 2x grid.sync between
// phases; __threadfence for cross-XCD visibility). Phase bodies are
// R15-exact (deform = R12-exact). The single rocprof row also decomposes
// kernel-work vs harness floor exactly.
// ---------------------------------------------------------------------------

typedef _Float16 half8 __attribute__((ext_vector_type(8)));
typedef __attribute__((ext_vector_type(4))) float floatx4;

// pack two floats -> f16x2 dword (RNE)
__device__ __forceinline__ unsigned int pack2h(float lo, float hi) {
    __half2 h = __floats2half2_rn(lo, hi);
    union { __half2 h; unsigned int u; } cv; cv.h = h;
    return cv.u;
}
// blend one f16x2 dword from 4 corners with broadcast __half2 weights
__device__ __forceinline__ unsigned int blend2h(unsigned int a, unsigned int b,
                                                unsigned int c, unsigned int d,
                                                const __half2* w) {
    union { unsigned int u; __half2 h; } A, B, C, D, O;
    A.u = a; B.u = b; C.u = c; D.u = d;
    __half2 s = __hmul2(A.h, w[0]);
    s = __hfma2(B.h, w[1], s);
    s = __hfma2(C.h, w[2], s);
    s = __hfma2(D.h, w[3], s);
    O.h = s;
    return O.u;
}

// Workspace layout (bytes)
#define OFF_DATAT 0u               // [8][16384][64] f16   = 16777216 B
#define OFF_OFFP  16777216u        // [8][9][3][16384] f32 = 14155776 B (dy,dx,mask)
#define OFF_WM    30932992u        // [64][576] f16        = 73728 B
#define OFF_W27   31006720u        // wq[9][2][2][4][16][8] f16 = 36864 B
#define OFF_B27   31043584u        // [32] f32             = 128 B
// total 31043712 B

// ---------------------------------------------------------------------------
// Mega-kernel. LDS union (32256 B):
//   phase A: tile  [64][65] f32          (16640 B)
//   phase C: pOff  [576] ushort4 @0      ( 4608 B)
//            pW    [576] uint4   @4608   ( 9216 B)
//            samp  [2][64][72] f16 @13824(18432 B)
// ---------------------------------------------------------------------------
__global__ __launch_bounds__(256, 4) void mega_k(const float* __restrict__ x,
                                                 unsigned short* __restrict__ xt,
                                                 const float* __restrict__ w,
                                                 const float* __restrict__ w_off,
                                                 const float* __restrict__ w_mod,
                                                 const float* __restrict__ b_off,
                                                 const float* __restrict__ b_mod,
                                                 unsigned short* __restrict__ wpackM,
                                                 unsigned short* __restrict__ wq,
                                                 float* __restrict__ bias27,
                                                 float* __restrict__ offP,
                                                 const float* __restrict__ bias,
                                                 float* __restrict__ out) {
    __shared__ __align__(16) char smem[32256];
    cg::grid_group grid = cg::this_grid();

    int tid  = threadIdx.x;
    int lane = tid & 63, wv = tid >> 6;
    int r = lane & 15, q = lane >> 4;

    // ================= PHASE A: transpose + weight pack =================
    {
        float (*tile)[65] = (float (*)[65])smem;
        for (int blk = blockIdx.x; blk < 2264; blk += gridDim.x) {
            if (blk < 2048) {                      // ---- transpose ----
                int b    = blk >> 8;
                int pos0 = (blk & 255) << 6;
                int g    = tid >> 6;
                for (int c = g; c < 64; c += 4)
                    tile[c][lane] = x[(((b << 6) + c) << 14) + pos0 + lane];
                __syncthreads();
                int c2 = lane & 31;
                for (int i = g; i < 32; i += 4) {
                    int pr = (i << 1) + (lane >> 5);
                    unsigned int d = pack2h(tile[c2 << 1][pr], tile[(c2 << 1) + 1][pr]);
                    *(unsigned int*)&xt[((size_t)((b << 14) + pos0 + pr) << 6) + (c2 << 1)] = d;
                }
                __syncthreads();                   // tile reads done before next iter
            } else {                               // ---- weight packing ----
                int t = (blk - 2048) * 256 + tid;
                if (t < 64 * 576) {
                    int o = t / 576, kk = t % 576;
                    int k = kk >> 6, c = kk & 63;
                    wpackM[t] = __half_as_ushort(__float2half_rn(w[(o * 64 + c) * 9 + k]));
                } else {
                    t -= 64 * 576;
                    if (t < 32 * 576) {
                        int o = t / 576, kk = t % 576;
                        int k = kk >> 6, c = kk & 63;
                        float v = 0.f;
                        if (o < 18)      v = w_off[(o * 64 + c) * 9 + k];
                        else if (o < 27) v = w_mod[((o - 18) * 64 + c) * 9 + k];
                        // wq: per (k,chh,s) 1KB block; (q,r,j) within
                        int s = o >> 4, rr = o & 15;
                        int chh = c >> 5, qq = (c >> 3) & 3, j = c & 7;
                        int dst = (((((k << 1) + chh) << 1) + s) << 9) + (qq << 7) + (rr << 3) + j;
                        wq[dst] = __half_as_ushort(__float2half_rn(v));
                        if (kk == 0) bias27[o] = (o < 18) ? b_off[o] : (o < 27 ? b_mod[o - 18] : 0.f);
                    }
                }
            }
        }
    }
    __threadfence();
    grid.sync();

    // ================= PHASE B: conv27 (LDS-free implicit GEMM) =================
    for (int blk = blockIdx.x; blk < 1024; blk += gridDim.x) {
        int b     = blk >> 7;
        int patch = blk & 127;
        int m     = patch >> 1;                    // row pair
        int h     = patch & 1;                     // col half

        const unsigned short* xb = xt + ((size_t)b << 20);
        int rb  = (m << 1) - 1;                    // top source row of patch
        int cxb = (h << 6) + (wv << 4) + r - 1;    // per-lane source col base
        int chq = (q << 3);                        // lane channel sub-chunk

        floatx4 acc[4] = {};                       // [s*2 + tr]
        #pragma unroll
        for (int k = 0; k < 9; ++k) {
            int ki = k / 3, kj = k % 3;
            #pragma unroll
            for (int chh = 0; chh < 2; ++chh) {
                int abase = ((((k << 1) + chh) << 1) << 9) + (lane << 3);
                half8 a0 = *(const half8*)&wq[abase];           // s=0 block
                half8 a1 = *(const half8*)&wq[abase + 512];     // s=1 block
                #pragma unroll
                for (int tr = 0; tr < 2; ++tr) {
                    int sy = rb + tr + ki;
                    int sx = cxb + kj;
                    half8 bf = {};
                    if ((unsigned)sy < 128u && (unsigned)sx < 128u)
                        bf = *(const half8*)&xb[(size_t)(((sy << 7) + sx) << 6) + (chh << 5) + chq];
                    acc[0 + tr] = __builtin_amdgcn_mfma_f32_16x16x32_f16(a0, bf, acc[0 + tr], 0, 0, 0);
                    acc[2 + tr] = __builtin_amdgcn_mfma_f32_16x16x32_f16(a1, bf, acc[2 + tr], 0, 0, 0);
                }
            }
        }

        #pragma unroll
        for (int s = 0; s < 2; ++s) {
            #pragma unroll
            for (int tr = 0; tr < 2; ++tr) {
                #pragma unroll
                for (int reg = 0; reg < 4; ++reg) {
                    int oc = (s << 4) + (q << 2) + reg;
                    if (oc >= 27) continue;
                    int pos = (((m << 1) + tr) << 7) + (h << 6) + (wv << 4) + r;
                    float v = acc[(s << 1) + tr][reg] + bias27[oc];
                    int kk, comp;
                    if (oc < 18) { kk = oc >> 1; comp = oc & 1; }
                    else         { kk = oc - 18; comp = 2; v = 2.f / (1.f + __expf(-v)); }
                    offP[(size_t)(((b * 9 + kk) * 3 + comp) << 14) + pos] = v;
                }
            }
        }
    }
    __threadfence();
    grid.sync();

    // ================= PHASE C: deform (R12-exact body, 2 tiles/block) =================
    {
        ushort4* pOff = (ushort4*)smem;                                     // [576]
        uint4*   pW   = (uint4*)(smem + 4608);                              // [576]
        unsigned short (*samp)[64][72] = (unsigned short (*)[64][72])(smem + 13824);
        int pg = lane >> 3;                        // position subgroup 0..7
        int j8 = lane & 7;                         // channel chunk (8 f16 = 16B)

        for (int tb = blockIdx.x; tb < 2048; tb += gridDim.x) {
            int b    = tb >> 8;
            int pos0 = (tb & 255) << 6;
            const char* xbb = (const char*)(xt + ((size_t)b << 20));

            // ---- phase 0: params (this __syncthreads also gates LDS reuse
            //      across tb iterations: all waves finished prior tile) ----
            for (int e = tid; e < 576; e += 256) {
                int k = e >> 6, p = e & 63;
                int pos = pos0 + p;
                const float* offk = offP + ((size_t)((b * 9 + k) * 3) << 14);
                float dy = offk[pos];
                float dx = offk[16384 + pos];
                float m  = offk[32768 + pos];
                float py = (float)(pos >> 7) + (float)(k / 3 - 1) + dy;
                float px = (float)(pos & 127) + (float)(k % 3 - 1) + dx;
                float y0f = floorf(py), x0f = floorf(px);
                int y0 = (int)y0f, x0 = (int)x0f;
                float wy1 = py - y0f, wx1 = px - x0f;
                float wy0 = 1.f - wy1, wx0 = 1.f - wx1;
                bool vy0 = (y0 >= 0) && (y0 < 128);
                bool vy1 = (y0 >= -1) && (y0 < 127);
                bool vx0 = (x0 >= 0) && (x0 < 128);
                bool vx1 = (x0 >= -1) && (x0 < 127);
                float w00 = (vy0 && vx0) ? m * wy0 * wx0 : 0.f;
                float w01 = (vy0 && vx1) ? m * wy0 * wx1 : 0.f;
                float w10 = (vy1 && vx0) ? m * wy1 * wx0 : 0.f;
                float w11 = (vy1 && vx1) ? m * wy1 * wx1 : 0.f;
                int y0c = min(max(y0, 0), 127), y1c = min(max(y0 + 1, 0), 127);
                int x0c = min(max(x0, 0), 127), x1c = min(max(x0 + 1, 0), 127);
                ushort4 io;
                io.x = (unsigned short)((y0c << 7) + x0c);
                io.y = (unsigned short)((y0c << 7) + x1c);
                io.z = (unsigned short)((y1c << 7) + x0c);
                io.w = (unsigned short)((y1c << 7) + x1c);
                pOff[e] = io;
                union { uint4 u; __half2 h[4]; } pw;
                pw.h[0] = __float2half2_rn(w00);
                pw.h[1] = __float2half2_rn(w01);
                pw.h[2] = __float2half2_rn(w10);
                pw.h[3] = __float2half2_rn(w11);
                pW[e] = pw.u;
            }
            __syncthreads();                        // pOff/pW ready

            floatx4 acc[4] = {};
            const char* xp = xbb + (j8 << 4);       // per-lane channel-chunk base
            const unsigned short* wrow = wpackM + ((wv << 4) + r) * 576 + (q << 3);

            uint4   c00[2][2], c01[2][2], c10[2][2], c11[2][2];  // [set][i]
            uint4   cwS[2][2];                      // weights per set
            ushort4 nio[2];                         // staged params (next issue)
            uint4   ncw[2];
            half8   afC[2], afN[2];                 // A-frags, current / next

            auto readParams = [&](int k) {
                #pragma unroll
                for (int i = 0; i < 2; ++i) {
                    int e  = (k << 6) + (wv << 4) + (i << 3) + pg;
                    nio[i] = pOff[e];
                    ncw[i] = pW[e];
                }
            };
            auto issueInto = [&](int s) {           // s compile-time at all call sites
                #pragma unroll
                for (int i = 0; i < 2; ++i) {
                    cwS[s][i] = ncw[i];
                    c00[s][i] = *(const uint4*)(xp + ((int)nio[i].x << 7));
                    c01[s][i] = *(const uint4*)(xp + ((int)nio[i].y << 7));
                    c10[s][i] = *(const uint4*)(xp + ((int)nio[i].z << 7));
                    c11[s][i] = *(const uint4*)(xp + ((int)nio[i].w << 7));
                }
            };
            auto blendStore = [&](int s, int buf) { // s, buf compile-time
                #pragma unroll
                for (int i = 0; i < 2; ++i) {
                    int p = (wv << 4) + (i << 3) + pg;
                    union { uint4 u; __half2 h[4]; } W; W.u = cwS[s][i];
                    uint4 o4;
                    o4.x = blend2h(c00[s][i].x, c01[s][i].x, c10[s][i].x, c11[s][i].x, W.h);
                    o4.y = blend2h(c00[s][i].y, c01[s][i].y, c10[s][i].y, c11[s][i].y, W.h);
                    o4.z = blend2h(c00[s][i].z, c01[s][i].z, c10[s][i].z, c11[s][i].z, W.h);
                    o4.w = blend2h(c00[s][i].w, c01[s][i].w, c10[s][i].w, c11[s][i].w, W.h);
                    *(uint4*)&samp[buf][p][j8 << 3] = o4;
                }
            };
            auto ldsBarrier = [&]() {
                asm volatile("s_waitcnt lgkmcnt(0)\n\ts_barrier" ::: "memory");
            };

            // prologue: taps 0 and 1 into the pipe; params(2) staged
            readParams(0); issueInto(0);
            readParams(1); issueInto(1);
            afC[0] = *(const half8*)&wrow[0];
            afC[1] = *(const half8*)&wrow[32];
            blendStore(0, 0);                       // blend tap0 -> samp[0]
            readParams(2);

            #pragma unroll
            for (int k = 0; k < 9; ++k) {
                if (k <= 6) issueInto(k & 1);       // corners for tap k+2
                if (k < 8) {
                    afN[0] = *(const half8*)&wrow[((k + 1) << 6)];
                    afN[1] = *(const half8*)&wrow[((k + 1) << 6) + 32];
                }
                ldsBarrier();                       // samp[k&1] complete block-wide
                #pragma unroll
                for (int ch = 0; ch < 2; ++ch) {
                    #pragma unroll
                    for (int nt = 0; nt < 4; ++nt) {
                        half8 bfrag = *(const half8*)&samp[k & 1][(nt << 4) + r][(ch << 5) + (q << 3)];
                        acc[nt] = __builtin_amdgcn_mfma_f32_16x16x32_f16(afC[ch], bfrag, acc[nt], 0, 0, 0);
                    }
                }
                if (k < 8) {
                    blendStore((k + 1) & 1, (k + 1) & 1);  // corners issued at body k-1
                    if (k <= 5) readParams(k + 3);  // params for issue at body k+1
                    afC[0] = afN[0];
                    afC[1] = afN[1];
                }
            }

            #pragma unroll
            for (int nt = 0; nt < 4; ++nt) {
                #pragma unroll
                for (int reg = 0; reg < 4; ++reg) {
                    int oc  = (wv << 4) + (q << 2) + reg;
                    int pos = pos0 + (nt << 4) + r;
                    float v = acc[nt][reg] + bias[oc];
                    out[(size_t)(((b << 6) + oc) << 14) + pos] = fmaxf(v, 0.f);
                }
            }
        }
    }
}

// ---------------------------------------------------------------------------
extern "C" void kernel_launch(void* const* d_in, const int* in_sizes, int n_in,
                              void* d_out, int out_size, void* d_ws, size_t ws_size,
                              hipStream_t stream) {
    const float* data  = (const float*)d_in[0];
    const float* w     = (const float*)d_in[1];
    const float* bias  = (const float*)d_in[2];
    const float* w_off = (const float*)d_in[3];
    const float* b_off = (const float*)d_in[4];
    const float* w_mod = (const float*)d_in[5];
    const float* b_mod = (const float*)d_in[6];
    float* out = (float*)d_out;

    char* ws = (char*)d_ws;
    unsigned short* dataT   = (unsigned short*)(ws + OFF_DATAT);
    float*          offP    = (float*)(ws + OFF_OFFP);
    unsigned short* wpackM  = (unsigned short*)(ws + OFF_WM);
    unsigned short* wq      = (unsigned short*)(ws + OFF_W27);
    float*          bias27  = (float*)(ws + OFF_B27);

    // Cooperative grid size: min(occupancy-derived co-resident blocks, 1024).
    // 1024 = 4 blocks/CU x 256 CUs; LDS 32256B/block -> 4/CU fits in 160KiB.
    static int s_grid = 0;
    if (s_grid == 0) {
        int nb = 0;
        if (hipOccupancyMaxActiveBlocksPerMultiprocessor(&nb, (const void*)mega_k,
                                                         256, 0) != hipSuccess || nb <= 0)
            nb = 4;
        long g = (long)nb * 256;                    // 256 CUs on MI355X
        s_grid = (int)(g < 1024 ? g : 1024);
    }

    void* args[] = { (void*)&data, (void*)&dataT, (void*)&w, (void*)&w_off,
                     (void*)&w_mod, (void*)&b_off, (void*)&b_mod, (void*)&wpackM,
                     (void*)&wq, (void*)&bias27, (void*)&offP, (void*)&bias,
                     (void*)&out };
    hipLaunchCooperativeKernel((const void*)mega_k, dim3(s_grid), dim3(256),
                               args, 0, stream);
}

// Round 6
// 196.114 us; speedup vs baseline: 2.2090x; 2.2090x over previous
//
#include <hip/hip_runtime.h>
#include <hip/hip_fp16.h>
#include <cstdint>

// ---------------------------------------------------------------------------
// SingleDeformConv on MI355X (gfx950)
// data (8,64,128,128) f32; w (64,64,3,3); b (64); w_off (18,64,3,3); b_off(18);
// w_mod (9,64,3,3); b_mod (9).  out = relu(deform_conv(...)) (8,64,128,128) f32
//
// R16 -> R17: cooperative mega-kernel was catastrophic (grid.sync ~100+us
// each, fence-forced L2 writebacks: FETCH 141MB/WRITE 158MB, all pipes idle).
// REVERT to R15 three-kernel structure (best total 160.7). Single lever this
// round: deform_main_k occupancy. Counters show all pipes thin (MFMA 7.8%,
// VALU 22%, HBM 21%) at Occupancy 25% (~2-3 blocks/CU) -- latency-bound
// candidate. 5 blocks/CU fits: LDS 5x32256=161280 <= 163840, VGPR 76 <= 102
// cap from __launch_bounds__(256,5) (the old (256,3) guarded a ~140-VGPR
// live set that no longer exists; now 76). If dur drops ~proportionally ->
// latency-bound confirmed; if flat -> TA/address-gen bound (uncounted pipe),
// next round reduces gather instruction count instead.
// ---------------------------------------------------------------------------

typedef _Float16 half8 __attribute__((ext_vector_type(8)));
typedef __attribute__((ext_vector_type(4))) float floatx4;

// pack two floats -> f16x2 dword (RNE)
__device__ __forceinline__ unsigned int pack2h(float lo, float hi) {
    __half2 h = __floats2half2_rn(lo, hi);
    union { __half2 h; unsigned int u; } cv; cv.h = h;
    return cv.u;
}
// blend one f16x2 dword from 4 corners with broadcast __half2 weights
__device__ __forceinline__ unsigned int blend2h(unsigned int a, unsigned int b,
                                                unsigned int c, unsigned int d,
                                                const __half2* w) {
    union { unsigned int u; __half2 h; } A, B, C, D, O;
    A.u = a; B.u = b; C.u = c; D.u = d;
    __half2 s = __hmul2(A.h, w[0]);
    s = __hfma2(B.h, w[1], s);
    s = __hfma2(C.h, w[2], s);
    s = __hfma2(D.h, w[3], s);
    O.h = s;
    return O.u;
}

// Workspace layout (bytes) — R12/R15 layout
#define OFF_DATAT 0u               // [8][16384][64] f16   = 16777216 B
#define OFF_OFFP  16777216u        // [8][9][3][16384] f32 = 14155776 B (dy,dx,mask)
#define OFF_WM    30932992u        // [64][576] f16        = 73728 B
#define OFF_W27   31006720u        // wq[9][2][2][4][16][8] f16 = 36864 B
#define OFF_B27   31043584u        // [32] f32             = 128 B
// total 31043712 B

// ---------------------------------------------------------------------------
// Kernel 1: prep = NCHW f32 -> NHWC f16 transpose (blocks 0..2047)
//           + weight packing / bias27 (blocks 2048..2263)
// wq layout: per (k, chh, s) a 512-half (1KB) block; within it offset
// q*128 + r*8 + j, where lane(r,q) of the MFMA A-frag reads halves
// [lane*8 .. lane*8+7]  ->  one fully-coalesced 1KB load per (k,chh,s).
// value at (k,chh,s,q,r,j) = W27[oc = s*16+r][c = chh*32+q*8+j][k]
// ---------------------------------------------------------------------------
__global__ __launch_bounds__(256) void prep_k(const float* __restrict__ x,
                                              unsigned short* __restrict__ xt,
                                              const float* __restrict__ w,
                                              const float* __restrict__ w_off,
                                              const float* __restrict__ w_mod,
                                              const float* __restrict__ b_off,
                                              const float* __restrict__ b_mod,
                                              unsigned short* __restrict__ wpackM,
                                              unsigned short* __restrict__ wq,
                                              float* __restrict__ bias27) {
    __shared__ float tile[64][65];
    int blk = blockIdx.x;
    if (blk < 2048) {                              // ---- transpose ----
        int b    = blk >> 8;
        int pos0 = (blk & 255) << 6;
        int lane = threadIdx.x & 63;
        int g    = threadIdx.x >> 6;
        for (int c = g; c < 64; c += 4)
            tile[c][lane] = x[(((b << 6) + c) << 14) + pos0 + lane];
        __syncthreads();
        int c2 = lane & 31;
        for (int i = g; i < 32; i += 4) {
            int pr = (i << 1) + (lane >> 5);
            unsigned int d = pack2h(tile[c2 << 1][pr], tile[(c2 << 1) + 1][pr]);
            *(unsigned int*)&xt[((size_t)((b << 14) + pos0 + pr) << 6) + (c2 << 1)] = d;
        }
        return;
    }
    // ---- weight packing ----
    int t = (blk - 2048) * 256 + threadIdx.x;
    if (t < 64 * 576) {
        int o = t / 576, kk = t % 576;
        int k = kk >> 6, c = kk & 63;
        wpackM[t] = __half_as_ushort(__float2half_rn(w[(o * 64 + c) * 9 + k]));
        return;
    }
    t -= 64 * 576;
    if (t < 32 * 576) {
        int o = t / 576, kk = t % 576;
        int k = kk >> 6, c = kk & 63;
        float v = 0.f;
        if (o < 18)      v = w_off[(o * 64 + c) * 9 + k];
        else if (o < 27) v = w_mod[((o - 18) * 64 + c) * 9 + k];
        // dest: (k, chh=c>>5, s=o>>4, q=(c>>3)&3, r=o&15, j=c&7)
        int s = o >> 4, r = o & 15;
        int chh = c >> 5, q = (c >> 3) & 3, j = c & 7;
        int dst = (((((k << 1) + chh) << 1) + s) << 9) + (q << 7) + (r << 3) + j;
        wq[dst] = __half_as_ushort(__float2half_rn(v));
        if (kk == 0) bias27[o] = (o < 18) ? b_off[o] : (o < 27 ? b_mod[o - 18] : 0.f);
    }
}

// ---------------------------------------------------------------------------
// Kernel 2: offset/mask conv (27 ch, padded to 32) — LDS-free implicit GEMM.
// Block: 256 thr, 2 rows x 64 cols patch. B-frags straight from xt (L1-hot:
// each xt line reused 9x by taps within the block). A-frags one coalesced
// 1KB load each from wq. No LDS, no barriers.
// ---------------------------------------------------------------------------
__global__ __launch_bounds__(256) void conv27_k(const unsigned short* __restrict__ xt,
                                                const unsigned short* __restrict__ wq,
                                                const float* __restrict__ bias27,
                                                float* __restrict__ offP) {
    int blk   = blockIdx.x;                         // 1024 = 8 b * 128 patches
    int b     = blk >> 7;
    int patch = blk & 127;
    int m     = patch >> 1;                         // row pair
    int h     = patch & 1;                          // col half
    int tid   = threadIdx.x;
    int lane  = tid & 63, wv = tid >> 6;
    int r = lane & 15, q = lane >> 4;

    const unsigned short* xb = xt + ((size_t)b << 20);
    int rb  = (m << 1) - 1;                         // top source row of patch
    int cxb = (h << 6) + (wv << 4) + r - 1;         // per-lane source col base
    int chq = (q << 3);                             // lane channel sub-chunk

    floatx4 acc[4] = {};                            // [s*2 + tr]
    #pragma unroll
    for (int k = 0; k < 9; ++k) {
        int ki = k / 3, kj = k % 3;
        #pragma unroll
        for (int chh = 0; chh < 2; ++chh) {
            int abase = ((((k << 1) + chh) << 1) << 9) + (lane << 3);
            half8 a0 = *(const half8*)&wq[abase];           // s=0 block
            half8 a1 = *(const half8*)&wq[abase + 512];     // s=1 block
            #pragma unroll
            for (int tr = 0; tr < 2; ++tr) {
                int sy = rb + tr + ki;
                int sx = cxb + kj;
                half8 bf = {};
                if ((unsigned)sy < 128u && (unsigned)sx < 128u)
                    bf = *(const half8*)&xb[(size_t)(((sy << 7) + sx) << 6) + (chh << 5) + chq];
                acc[0 + tr] = __builtin_amdgcn_mfma_f32_16x16x32_f16(a0, bf, acc[0 + tr], 0, 0, 0);
                acc[2 + tr] = __builtin_amdgcn_mfma_f32_16x16x32_f16(a1, bf, acc[2 + tr], 0, 0, 0);
            }
        }
    }

    #pragma unroll
    for (int s = 0; s < 2; ++s) {
        #pragma unroll
        for (int tr = 0; tr < 2; ++tr) {
            #pragma unroll
            for (int reg = 0; reg < 4; ++reg) {
                int oc = (s << 4) + (q << 2) + reg;
                if (oc >= 27) continue;
                int pos = (((m << 1) + tr) << 7) + (h << 6) + (wv << 4) + r;
                float v = acc[(s << 1) + tr][reg] + bias27[oc];
                int kk, comp;
                if (oc < 18) { kk = oc >> 1; comp = oc & 1; }
                else         { kk = oc - 18; comp = 2; v = 2.f / (1.f + __expf(-v)); }
                offP[(size_t)(((b * 9 + kk) * 3 + comp) << 14) + pos] = v;
            }
        }
    }
}

// ---------------------------------------------------------------------------
// Kernel 3: main deformable conv — R12-exact two-tap pipelined f16 datapath.
// Occupancy experiment: __launch_bounds__(256,5) -> 5 blocks/CU feasible
// (LDS 5x32256=161280 <= 163840; VGPR 76 <= 102 cap).
// ---------------------------------------------------------------------------
__global__ __launch_bounds__(256, 5) void deform_main_k(const unsigned short* __restrict__ xt,
                                                        const unsigned short* __restrict__ wpackM,
                                                        const float* __restrict__ offP,
                                                        const float* __restrict__ bias,
                                                        float* __restrict__ out) {
    __shared__ ushort4 pOff[576];                   // 4608 B  corner pos-indices
    __shared__ uint4   pW[576];                     // 9216 B  4x f16x2 weights
    __shared__ unsigned short samp[2][64][72];      // 18432 B B-tile (double buf)
    int blk  = blockIdx.x;                          // 2048 = 8 b * 256
    int b    = blk >> 8;
    int pos0 = (blk & 255) << 6;
    int tid  = threadIdx.x;
    int lane = tid & 63, wv = tid >> 6;
    int r = lane & 15, q = lane >> 4;
    int pg = lane >> 3;                             // position subgroup 0..7
    int j8 = lane & 7;                              // channel chunk (8 f16 = 16B)

    const char* xbb = (const char*)(xt + ((size_t)b << 20));

    // ---- phase 0: params, one thread per (tap,pos) entry ----
    for (int e = tid; e < 576; e += 256) {
        int k = e >> 6, p = e & 63;
        int pos = pos0 + p;
        const float* offk = offP + ((size_t)((b * 9 + k) * 3) << 14);
        float dy = offk[pos];
        float dx = offk[16384 + pos];
        float m  = offk[32768 + pos];
        float py = (float)(pos >> 7) + (float)(k / 3 - 1) + dy;
        float px = (float)(pos & 127) + (float)(k % 3 - 1) + dx;
        float y0f = floorf(py), x0f = floorf(px);
        int y0 = (int)y0f, x0 = (int)x0f;
        float wy1 = py - y0f, wx1 = px - x0f;
        float wy0 = 1.f - wy1, wx0 = 1.f - wx1;
        bool vy0 = (y0 >= 0) && (y0 < 128);
        bool vy1 = (y0 >= -1) && (y0 < 127);
        bool vx0 = (x0 >= 0) && (x0 < 128);
        bool vx1 = (x0 >= -1) && (x0 < 127);
        float w00 = (vy0 && vx0) ? m * wy0 * wx0 : 0.f;
        float w01 = (vy0 && vx1) ? m * wy0 * wx1 : 0.f;
        float w10 = (vy1 && vx0) ? m * wy1 * wx0 : 0.f;
        float w11 = (vy1 && vx1) ? m * wy1 * wx1 : 0.f;
        int y0c = min(max(y0, 0), 127), y1c = min(max(y0 + 1, 0), 127);
        int x0c = min(max(x0, 0), 127), x1c = min(max(x0 + 1, 0), 127);
        ushort4 io;
        io.x = (unsigned short)((y0c << 7) + x0c);
        io.y = (unsigned short)((y0c << 7) + x1c);
        io.z = (unsigned short)((y1c << 7) + x0c);
        io.w = (unsigned short)((y1c << 7) + x1c);
        pOff[e] = io;
        union { uint4 u; __half2 h[4]; } pw;
        pw.h[0] = __float2half2_rn(w00);
        pw.h[1] = __float2half2_rn(w01);
        pw.h[2] = __float2half2_rn(w10);
        pw.h[3] = __float2half2_rn(w11);
        pW[e] = pw.u;
    }
    __syncthreads();                                // pOff/pW ready

    floatx4 acc[4] = {};
    const char* xp = xbb + (j8 << 4);               // per-lane channel-chunk base
    const unsigned short* wrow = wpackM + ((wv << 4) + r) * 576 + (q << 3);

    uint4   c00[2][2], c01[2][2], c10[2][2], c11[2][2];  // [set][i]
    uint4   cwS[2][2];                              // weights per set
    ushort4 nio[2];                                 // staged params (next issue)
    uint4   ncw[2];
    half8   afC[2], afN[2];                         // A-frags, current / next

    auto readParams = [&](int k) {
        #pragma unroll
        for (int i = 0; i < 2; ++i) {
            int e  = (k << 6) + (wv << 4) + (i << 3) + pg;
            nio[i] = pOff[e];
            ncw[i] = pW[e];
        }
    };
    auto issueInto = [&](int s) {                   // s is compile-time at all call sites
        #pragma unroll
        for (int i = 0; i < 2; ++i) {
            cwS[s][i] = ncw[i];
            c00[s][i] = *(const uint4*)(xp + ((int)nio[i].x << 7));
            c01[s][i] = *(const uint4*)(xp + ((int)nio[i].y << 7));
            c10[s][i] = *(const uint4*)(xp + ((int)nio[i].z << 7));
            c11[s][i] = *(const uint4*)(xp + ((int)nio[i].w << 7));
        }
    };
    auto blendStore = [&](int s, int buf) {         // s, buf compile-time
        #pragma unroll
        for (int i = 0; i < 2; ++i) {
            int p = (wv << 4) + (i << 3) + pg;
            union { uint4 u; __half2 h[4]; } W; W.u = cwS[s][i];
            uint4 o4;
            o4.x = blend2h(c00[s][i].x, c01[s][i].x, c10[s][i].x, c11[s][i].x, W.h);
            o4.y = blend2h(c00[s][i].y, c01[s][i].y, c10[s][i].y, c11[s][i].y, W.h);
            o4.z = blend2h(c00[s][i].z, c01[s][i].z, c10[s][i].z, c11[s][i].z, W.h);
            o4.w = blend2h(c00[s][i].w, c01[s][i].w, c10[s][i].w, c11[s][i].w, W.h);
            *(uint4*)&samp[buf][p][j8 << 3] = o4;
        }
    };

    // LDS-only barrier: commit this wave's ds_writes (lgkmcnt), then barrier.
    auto ldsBarrier = [&]() {
        asm volatile("s_waitcnt lgkmcnt(0)\n\ts_barrier" ::: "memory");
    };

    // prologue: taps 0 and 1 into the pipe; params(2) staged
    readParams(0); issueInto(0);
    readParams(1); issueInto(1);
    afC[0] = *(const half8*)&wrow[0];
    afC[1] = *(const half8*)&wrow[32];
    blendStore(0, 0);                               // blend tap0 -> samp[0]
    readParams(2);

    #pragma unroll
    for (int k = 0; k < 9; ++k) {
        if (k <= 6) issueInto(k & 1);               // corners for tap k+2
        if (k < 8) {
            afN[0] = *(const half8*)&wrow[((k + 1) << 6)];
            afN[1] = *(const half8*)&wrow[((k + 1) << 6) + 32];
        }
        ldsBarrier();                               // samp[k&1] complete block-wide
        #pragma unroll
        for (int ch = 0; ch < 2; ++ch) {
            #pragma unroll
            for (int nt = 0; nt < 4; ++nt) {
                half8 bfrag = *(const half8*)&samp[k & 1][(nt << 4) + r][(ch << 5) + (q << 3)];
                acc[nt] = __builtin_amdgcn_mfma_f32_16x16x32_f16(afC[ch], bfrag, acc[nt], 0, 0, 0);
            }
        }
        if (k < 8) {
            blendStore((k + 1) & 1, (k + 1) & 1);   // corners issued at body k-1
            if (k <= 5) readParams(k + 3);          // params for issue at body k+1
            afC[0] = afN[0];
            afC[1] = afN[1];
        }
    }

    #pragma unroll
    for (int nt = 0; nt < 4; ++nt) {
        #pragma unroll
        for (int reg = 0; reg < 4; ++reg) {
            int oc  = (wv << 4) + (q << 2) + reg;
            int pos = pos0 + (nt << 4) + r;
            float v = acc[nt][reg] + bias[oc];
            out[(size_t)(((b << 6) + oc) << 14) + pos] = fmaxf(v, 0.f);
        }
    }
}

// ---------------------------------------------------------------------------
extern "C" void kernel_launch(void* const* d_in, const int* in_sizes, int n_in,
                              void* d_out, int out_size, void* d_ws, size_t ws_size,
                              hipStream_t stream) {
    const float* data  = (const float*)d_in[0];
    const float* w     = (const float*)d_in[1];
    const float* bias  = (const float*)d_in[2];
    const float* w_off = (const float*)d_in[3];
    const float* b_off = (const float*)d_in[4];
    const float* w_mod = (const float*)d_in[5];
    const float* b_mod = (const float*)d_in[6];
    float* out = (float*)d_out;

    char* ws = (char*)d_ws;
    unsigned short* dataT   = (unsigned short*)(ws + OFF_DATAT);
    float*          offP    = (float*)(ws + OFF_OFFP);
    unsigned short* wpackM  = (unsigned short*)(ws + OFF_WM);
    unsigned short* wq      = (unsigned short*)(ws + OFF_W27);
    float*          bias27  = (float*)(ws + OFF_B27);

    prep_k<<<2264, 256, 0, stream>>>(data, dataT, w, w_off, w_mod,
                                     b_off, b_mod, wpackM, wq, bias27);
    conv27_k<<<1024, 256, 0, stream>>>(dataT, wq, bias27, offP);
    deform_main_k<<<2048, 256, 0, stream>>>(dataT, wpackM, offP, bias, out);
}

// Round 7
// 166.268 us; speedup vs baseline: 2.6055x; 1.1795x over previous
//
#include <hip/hip_runtime.h>
#include <hip/hip_fp16.h>
#include <cstdint>

// ---------------------------------------------------------------------------
// SingleDeformConv on MI355X (gfx950)
// data (8,64,128,128) f32; w (64,64,3,3); b (64); w_off (18,64,3,3); b_off(18);
// w_mod (9,64,3,3); b_mod (9).  out = relu(deform_conv(...)) (8,64,128,128) f32
//
// R17 -> R18: barrier-free deform. R17's (256,5) cap caused spills (VGPR 48,
// +210MB scratch traffic) -- reverted. This round removes the REASON deform
// needs its 9-barrier samp round-trip: swap the wave decomposition so each
// wave owns 16 positions x ALL 64 out-channels. Its B-frags then come from
// its OWN blend output via ds_bpermute (dst lane q*16+r pulls chunk 4ch+q of
// pos r from src lane (r&7)*8+4ch+q, reg i=r>>3 via cndmask): 16 bperm +
// 8 sel per tap REPLACES 2 ds_write_b128 + 8 ds_read_b128 + barrier.
// Deletes all in-loop barriers, all samp bank conflicts (2.36M cyc), 18.4KB
// LDS. A-frags now 4 oc-tiles/tap from wpackM repacked (by prep) into the
// conv27-proven 1KB-coalesced layout: one dwordx4-coalesced load each,
// L1-hot. launch_bounds(256,4): cap 128 >= ~110 live, no spill.
// ---------------------------------------------------------------------------

typedef _Float16 half8 __attribute__((ext_vector_type(8)));
typedef __attribute__((ext_vector_type(4))) float floatx4;

// pack two floats -> f16x2 dword (RNE)
__device__ __forceinline__ unsigned int pack2h(float lo, float hi) {
    __half2 h = __floats2half2_rn(lo, hi);
    union { __half2 h; unsigned int u; } cv; cv.h = h;
    return cv.u;
}
// blend one f16x2 dword from 4 corners with broadcast __half2 weights
__device__ __forceinline__ unsigned int blend2h(unsigned int a, unsigned int b,
                                                unsigned int c, unsigned int d,
                                                const __half2* w) {
    union { unsigned int u; __half2 h; } A, B, C, D, O;
    A.u = a; B.u = b; C.u = c; D.u = d;
    __half2 s = __hmul2(A.h, w[0]);
    s = __hfma2(B.h, w[1], s);
    s = __hfma2(C.h, w[2], s);
    s = __hfma2(D.h, w[3], s);
    O.h = s;
    return O.u;
}

// Workspace layout (bytes)
#define OFF_DATAT 0u               // [8][16384][64] f16   = 16777216 B
#define OFF_OFFP  16777216u        // [8][9][3][16384] f32 = 14155776 B (dy,dx,mask)
#define OFF_WM    30932992u        // wqM[9][4][2][512] f16 = 73728 B (MFMA-native)
#define OFF_W27   31006720u        // wq[9][2][2][4][16][8] f16 = 36864 B
#define OFF_B27   31043584u        // [32] f32             = 128 B
// total 31043712 B

// ---------------------------------------------------------------------------
// Kernel 1: prep = NCHW f32 -> NHWC f16 transpose (blocks 0..2047)
//           + weight packing / bias27 (blocks 2048..2263)
// wqM layout (main weights, NEW): per (k, octile, ch) a 512-half (1KB) block;
// within it lane(q*16+r)*8 + j = w[oc=octile*16+r][c=ch*32+q*8+j][k]
// -> each A-frag load in deform is ONE fully-coalesced 1KB instruction.
// wq layout (27-ch weights): unchanged from R15 (proven).
// ---------------------------------------------------------------------------
__global__ __launch_bounds__(256) void prep_k(const float* __restrict__ x,
                                              unsigned short* __restrict__ xt,
                                              const float* __restrict__ w,
                                              const float* __restrict__ w_off,
                                              const float* __restrict__ w_mod,
                                              const float* __restrict__ b_off,
                                              const float* __restrict__ b_mod,
                                              unsigned short* __restrict__ wqM,
                                              unsigned short* __restrict__ wq,
                                              float* __restrict__ bias27) {
    __shared__ float tile[64][65];
    int blk = blockIdx.x;
    if (blk < 2048) {                              // ---- transpose ----
        int b    = blk >> 8;
        int pos0 = (blk & 255) << 6;
        int lane = threadIdx.x & 63;
        int g    = threadIdx.x >> 6;
        for (int c = g; c < 64; c += 4)
            tile[c][lane] = x[(((b << 6) + c) << 14) + pos0 + lane];
        __syncthreads();
        int c2 = lane & 31;
        for (int i = g; i < 32; i += 4) {
            int pr = (i << 1) + (lane >> 5);
            unsigned int d = pack2h(tile[c2 << 1][pr], tile[(c2 << 1) + 1][pr]);
            *(unsigned int*)&xt[((size_t)((b << 14) + pos0 + pr) << 6) + (c2 << 1)] = d;
        }
        return;
    }
    // ---- weight packing ----
    int t = (blk - 2048) * 256 + threadIdx.x;
    if (t < 64 * 576) {
        int o = t / 576, kk = t % 576;
        int k = kk >> 6, c = kk & 63;
        // dest: block (k*8 + octile*2 + ch), offset (q*16+r)*8 + j
        int octile = o >> 4, rr = o & 15;
        int chh = c >> 5, qq = (c >> 3) & 3, jj = c & 7;
        int dst = (((k << 3) + (octile << 1) + chh) << 9) + (qq << 7) + (rr << 3) + jj;
        wqM[dst] = __half_as_ushort(__float2half_rn(w[(o * 64 + c) * 9 + k]));
        return;
    }
    t -= 64 * 576;
    if (t < 32 * 576) {
        int o = t / 576, kk = t % 576;
        int k = kk >> 6, c = kk & 63;
        float v = 0.f;
        if (o < 18)      v = w_off[(o * 64 + c) * 9 + k];
        else if (o < 27) v = w_mod[((o - 18) * 64 + c) * 9 + k];
        int s = o >> 4, r = o & 15;
        int chh = c >> 5, q = (c >> 3) & 3, j = c & 7;
        int dst = (((((k << 1) + chh) << 1) + s) << 9) + (q << 7) + (r << 3) + j;
        wq[dst] = __half_as_ushort(__float2half_rn(v));
        if (kk == 0) bias27[o] = (o < 18) ? b_off[o] : (o < 27 ? b_mod[o - 18] : 0.f);
    }
}

// ---------------------------------------------------------------------------
// Kernel 2: offset/mask conv (27 ch, padded to 32) — LDS-free implicit GEMM.
// Unchanged from R15.
// ---------------------------------------------------------------------------
__global__ __launch_bounds__(256) void conv27_k(const unsigned short* __restrict__ xt,
                                                const unsigned short* __restrict__ wq,
                                                const float* __restrict__ bias27,
                                                float* __restrict__ offP) {
    int blk   = blockIdx.x;                         // 1024 = 8 b * 128 patches
    int b     = blk >> 7;
    int patch = blk & 127;
    int m     = patch >> 1;                         // row pair
    int h     = patch & 1;                          // col half
    int tid   = threadIdx.x;
    int lane  = tid & 63, wv = tid >> 6;
    int r = lane & 15, q = lane >> 4;

    const unsigned short* xb = xt + ((size_t)b << 20);
    int rb  = (m << 1) - 1;                         // top source row of patch
    int cxb = (h << 6) + (wv << 4) + r - 1;         // per-lane source col base
    int chq = (q << 3);                             // lane channel sub-chunk

    floatx4 acc[4] = {};                            // [s*2 + tr]
    #pragma unroll
    for (int k = 0; k < 9; ++k) {
        int ki = k / 3, kj = k % 3;
        #pragma unroll
        for (int chh = 0; chh < 2; ++chh) {
            int abase = ((((k << 1) + chh) << 1) << 9) + (lane << 3);
            half8 a0 = *(const half8*)&wq[abase];           // s=0 block
            half8 a1 = *(const half8*)&wq[abase + 512];     // s=1 block
            #pragma unroll
            for (int tr = 0; tr < 2; ++tr) {
                int sy = rb + tr + ki;
                int sx = cxb + kj;
                half8 bf = {};
                if ((unsigned)sy < 128u && (unsigned)sx < 128u)
                    bf = *(const half8*)&xb[(size_t)(((sy << 7) + sx) << 6) + (chh << 5) + chq];
                acc[0 + tr] = __builtin_amdgcn_mfma_f32_16x16x32_f16(a0, bf, acc[0 + tr], 0, 0, 0);
                acc[2 + tr] = __builtin_amdgcn_mfma_f32_16x16x32_f16(a1, bf, acc[2 + tr], 0, 0, 0);
            }
        }
    }

    #pragma unroll
    for (int s = 0; s < 2; ++s) {
        #pragma unroll
        for (int tr = 0; tr < 2; ++tr) {
            #pragma unroll
            for (int reg = 0; reg < 4; ++reg) {
                int oc = (s << 4) + (q << 2) + reg;
                if (oc >= 27) continue;
                int pos = (((m << 1) + tr) << 7) + (h << 6) + (wv << 4) + r;
                float v = acc[(s << 1) + tr][reg] + bias27[oc];
                int kk, comp;
                if (oc < 18) { kk = oc >> 1; comp = oc & 1; }
                else         { kk = oc - 18; comp = 2; v = 2.f / (1.f + __expf(-v)); }
                offP[(size_t)(((b * 9 + kk) * 3 + comp) << 14) + pos] = v;
            }
        }
    }
}

// ---------------------------------------------------------------------------
// Kernel 3: main deformable conv — BARRIER-FREE wave-local datapath.
// Wave wv owns positions [16wv,16wv+16) x all 64 oc. Gather+blend unchanged
// (lane pg,j8 blends chunk j8 of pos {pg, 8+pg}); B-frag built in-register
// via ds_bpermute (no samp LDS, no in-loop barrier). A-frags: 8 coalesced
// 1KB loads/tap from wqM. LDS = pOff/pW only (13824 B).
// ---------------------------------------------------------------------------
__global__ __launch_bounds__(256, 4) void deform_main_k(const unsigned short* __restrict__ xt,
                                                        const unsigned short* __restrict__ wqM,
                                                        const float* __restrict__ offP,
                                                        const float* __restrict__ bias,
                                                        float* __restrict__ out) {
    __shared__ ushort4 pOff[576];                   // 4608 B  corner pos-indices
    __shared__ uint4   pW[576];                     // 9216 B  4x f16x2 weights
    int blk  = blockIdx.x;                          // 2048 = 8 b * 256
    int b    = blk >> 8;
    int pos0 = (blk & 255) << 6;
    int tid  = threadIdx.x;
    int lane = tid & 63, wv = tid >> 6;
    int r = lane & 15, q = lane >> 4;
    int pg = lane >> 3;                             // position subgroup 0..7
    int j8 = lane & 7;                              // channel chunk (8 f16 = 16B)

    const char* xbb = (const char*)(xt + ((size_t)b << 20));

    // ---- phase 0: params, one thread per (tap,pos) entry (unchanged) ----
    for (int e = tid; e < 576; e += 256) {
        int k = e >> 6, p = e & 63;
        int pos = pos0 + p;
        const float* offk = offP + ((size_t)((b * 9 + k) * 3) << 14);
        float dy = offk[pos];
        float dx = offk[16384 + pos];
        float m  = offk[32768 + pos];
        float py = (float)(pos >> 7) + (float)(k / 3 - 1) + dy;
        float px = (float)(pos & 127) + (float)(k % 3 - 1) + dx;
        float y0f = floorf(py), x0f = floorf(px);
        int y0 = (int)y0f, x0 = (int)x0f;
        float wy1 = py - y0f, wx1 = px - x0f;
        float wy0 = 1.f - wy1, wx0 = 1.f - wx1;
        bool vy0 = (y0 >= 0) && (y0 < 128);
        bool vy1 = (y0 >= -1) && (y0 < 127);
        bool vx0 = (x0 >= 0) && (x0 < 128);
        bool vx1 = (x0 >= -1) && (x0 < 127);
        float w00 = (vy0 && vx0) ? m * wy0 * wx0 : 0.f;
        float w01 = (vy0 && vx1) ? m * wy0 * wx1 : 0.f;
        float w10 = (vy1 && vx0) ? m * wy1 * wx0 : 0.f;
        float w11 = (vy1 && vx1) ? m * wy1 * wx1 : 0.f;
        int y0c = min(max(y0, 0), 127), y1c = min(max(y0 + 1, 0), 127);
        int x0c = min(max(x0, 0), 127), x1c = min(max(x0 + 1, 0), 127);
        ushort4 io;
        io.x = (unsigned short)((y0c << 7) + x0c);
        io.y = (unsigned short)((y0c << 7) + x1c);
        io.z = (unsigned short)((y1c << 7) + x0c);
        io.w = (unsigned short)((y1c << 7) + x1c);
        pOff[e] = io;
        union { uint4 u; __half2 h[4]; } pw;
        pw.h[0] = __float2half2_rn(w00);
        pw.h[1] = __float2half2_rn(w01);
        pw.h[2] = __float2half2_rn(w10);
        pw.h[3] = __float2half2_rn(w11);
        pW[e] = pw.u;
    }
    __syncthreads();                                // pOff/pW ready (only barrier)

    floatx4 acc[4] = {};                            // [octile]
    const char* xp = xbb + (j8 << 4);               // per-lane channel-chunk base

    // bpermute byte-indices: src lane S = (r&7)*8 + 4ch + q  ->  index = S*4
    int idxc0 = ((r & 7) << 5) + (q << 2);          // ch=0
    int idxc1 = idxc0 + 16;                         // ch=1

    uint4   c00[2][2], c01[2][2], c10[2][2], c11[2][2];  // [set][i]
    uint4   cwS[2][2];                              // weights per set
    ushort4 nio[2];                                 // staged params (next issue)
    uint4   ncw[2];

    auto readParams = [&](int k) {
        #pragma unroll
        for (int i = 0; i < 2; ++i) {
            int e  = (k << 6) + (wv << 4) + (i << 3) + pg;
            nio[i] = pOff[e];
            ncw[i] = pW[e];
        }
    };
    auto issueInto = [&](int s) {                   // s compile-time at all call sites
        #pragma unroll
        for (int i = 0; i < 2; ++i) {
            cwS[s][i] = ncw[i];
            c00[s][i] = *(const uint4*)(xp + ((int)nio[i].x << 7));
            c01[s][i] = *(const uint4*)(xp + ((int)nio[i].y << 7));
            c10[s][i] = *(const uint4*)(xp + ((int)nio[i].z << 7));
            c11[s][i] = *(const uint4*)(xp + ((int)nio[i].w << 7));
        }
    };
    // dst dword: pull src dword from o4[i=r>>3] at lane idx/4
    auto bperm1 = [&](int idx, unsigned int lo, unsigned int hi) -> unsigned int {
        int t0 = __builtin_amdgcn_ds_bpermute(idx, (int)lo);
        int t1 = __builtin_amdgcn_ds_bpermute(idx, (int)hi);
        return (r >= 8) ? (unsigned int)t1 : (unsigned int)t0;
    };

    // prologue: tap0 gathers in flight; params(1) staged
    readParams(0); issueInto(0);
    readParams(1);

    #pragma unroll
    for (int k = 0; k < 9; ++k) {
        if (k < 8) issueInto((k + 1) & 1);          // next-tap gathers in flight
        if (k <= 6) readParams(k + 2);              // params for next issue

        // blend current set -> o4[i] (chunk j8 of pos {16wv+pg, 16wv+8+pg})
        uint4 o4[2];
        {
            const int s = k & 1;                    // compile-time (unrolled)
            #pragma unroll
            for (int i = 0; i < 2; ++i) {
                union { uint4 u; __half2 h[4]; } W; W.u = cwS[s][i];
                o4[i].x = blend2h(c00[s][i].x, c01[s][i].x, c10[s][i].x, c11[s][i].x, W.h);
                o4[i].y = blend2h(c00[s][i].y, c01[s][i].y, c10[s][i].y, c11[s][i].y, W.h);
                o4[i].z = blend2h(c00[s][i].z, c01[s][i].z, c10[s][i].z, c11[s][i].z, W.h);
                o4[i].w = blend2h(c00[s][i].w, c01[s][i].w, c10[s][i].w, c11[s][i].w, W.h);
            }
        }

        // B-frags in-register: lane (r,q) <- chunk 4ch+q of pos r (wave-local)
        uint4 bfu0, bfu1;
        bfu0.x = bperm1(idxc0, o4[0].x, o4[1].x);
        bfu0.y = bperm1(idxc0, o4[0].y, o4[1].y);
        bfu0.z = bperm1(idxc0, o4[0].z, o4[1].z);
        bfu0.w = bperm1(idxc0, o4[0].w, o4[1].w);
        bfu1.x = bperm1(idxc1, o4[0].x, o4[1].x);
        bfu1.y = bperm1(idxc1, o4[0].y, o4[1].y);
        bfu1.z = bperm1(idxc1, o4[0].z, o4[1].z);
        bfu1.w = bperm1(idxc1, o4[0].w, o4[1].w);
        union { uint4 u; half8 h; } B0, B1;
        B0.u = bfu0; B1.u = bfu1;

        // MFMA: 4 oc-tiles x 2 ch; A = one coalesced 1KB load each (L1-hot)
        #pragma unroll
        for (int ot = 0; ot < 4; ++ot) {
            half8 a0 = *(const half8*)&wqM[(((k << 3) + (ot << 1) + 0) << 9) + (lane << 3)];
            half8 a1 = *(const half8*)&wqM[(((k << 3) + (ot << 1) + 1) << 9) + (lane << 3)];
            acc[ot] = __builtin_amdgcn_mfma_f32_16x16x32_f16(a0, B0.h, acc[ot], 0, 0, 0);
            acc[ot] = __builtin_amdgcn_mfma_f32_16x16x32_f16(a1, B1.h, acc[ot], 0, 0, 0);
        }
    }

    // epilogue: C lane (r,q) reg: oc = ot*16 + q*4 + reg, pos = pos0 + wv*16 + r
    #pragma unroll
    for (int ot = 0; ot < 4; ++ot) {
        #pragma unroll
        for (int reg = 0; reg < 4; ++reg) {
            int oc  = (ot << 4) + (q << 2) + reg;
            int pos = pos0 + (wv << 4) + r;
            float v = acc[ot][reg] + bias[oc];
            out[(size_t)(((b << 6) + oc) << 14) + pos] = fmaxf(v, 0.f);
        }
    }
}

// ---------------------------------------------------------------------------
extern "C" void kernel_launch(void* const* d_in, const int* in_sizes, int n_in,
                              void* d_out, int out_size, void* d_ws, size_t ws_size,
                              hipStream_t stream) {
    const float* data  = (const float*)d_in[0];
    const float* w     = (const float*)d_in[1];
    const float* bias  = (const float*)d_in[2];
    const float* w_off = (const float*)d_in[3];
    const float* b_off = (const float*)d_in[4];
    const float* w_mod = (const float*)d_in[5];
    const float* b_mod = (const float*)d_in[6];
    float* out = (float*)d_out;

    char* ws = (char*)d_ws;
    unsigned short* dataT   = (unsigned short*)(ws + OFF_DATAT);
    float*          offP    = (float*)(ws + OFF_OFFP);
    unsigned short* wqM     = (unsigned short*)(ws + OFF_WM);
    unsigned short* wq      = (unsigned short*)(ws + OFF_W27);
    float*          bias27  = (float*)(ws + OFF_B27);

    prep_k<<<2264, 256, 0, stream>>>(data, dataT, w, w_off, w_mod,
                                     b_off, b_mod, wqM, wq, bias27);
    conv27_k<<<1024, 256, 0, stream>>>(dataT, wq, bias27, offP);
    deform_main_k<<<2048, 256, 0, stream>>>(dataT, wqM, offP, bias, out);
}

// Round 8
// 164.887 us; speedup vs baseline: 2.6273x; 1.0084x over previous
//
#include <hip/hip_runtime.h>
#include <hip/hip_fp16.h>
#include <cstdint>

// ---------------------------------------------------------------------------
// SingleDeformConv on MI355X (gfx950)
// data (8,64,128,128) f32; w (64,64,3,3); b (64); w_off (18,64,3,3); b_off(18);
// w_mod (9,64,3,3); b_mod (9).  out = relu(deform_conv(...)) (8,64,128,128) f32
//
// R18 -> R19: revert to R15 structure (best 160.7; R18's bpermute path was
// +6us: occupancy 38% didn't help -> not latency-bound; identical 2.36M
// conflict count across disjoint LDS patterns -> largely structural).
// Two micro-levers this round:
//  (1) deform samp: flat layout [nt][ch][q][r][j] so every B-frag
//      ds_read_b128 is 1KB lane-linear contiguous (canonical conflict-free);
//      blendStore still one contiguous b128 per i. -2KB LDS.
//  (2) prep transpose: store dwordx4 (8 ch/thread-entry) instead of 8x 4B
//      stores -- wave writes 1KB contiguous per instr.
// Everything else R15-exact. Decision rule: if conflicts collapse but deform
// moves <1.5us -> deform is at its practical floor; remaining time is the
// 3-phase dependency chain + harness constant.
// ---------------------------------------------------------------------------

typedef _Float16 half8 __attribute__((ext_vector_type(8)));
typedef __attribute__((ext_vector_type(4))) float floatx4;

// pack two floats -> f16x2 dword (RNE)
__device__ __forceinline__ unsigned int pack2h(float lo, float hi) {
    __half2 h = __floats2half2_rn(lo, hi);
    union { __half2 h; unsigned int u; } cv; cv.h = h;
    return cv.u;
}
// blend one f16x2 dword from 4 corners with broadcast __half2 weights
__device__ __forceinline__ unsigned int blend2h(unsigned int a, unsigned int b,
                                                unsigned int c, unsigned int d,
                                                const __half2* w) {
    union { unsigned int u; __half2 h; } A, B, C, D, O;
    A.u = a; B.u = b; C.u = c; D.u = d;
    __half2 s = __hmul2(A.h, w[0]);
    s = __hfma2(B.h, w[1], s);
    s = __hfma2(C.h, w[2], s);
    s = __hfma2(D.h, w[3], s);
    O.h = s;
    return O.u;
}

// Workspace layout (bytes) — R15 layout
#define OFF_DATAT 0u               // [8][16384][64] f16   = 16777216 B
#define OFF_OFFP  16777216u        // [8][9][3][16384] f32 = 14155776 B (dy,dx,mask)
#define OFF_WM    30932992u        // [64][576] f16        = 73728 B
#define OFF_W27   31006720u        // wq[9][2][2][4][16][8] f16 = 36864 B
#define OFF_B27   31043584u        // [32] f32             = 128 B
// total 31043712 B

// ---------------------------------------------------------------------------
// Kernel 1: prep = NCHW f32 -> NHWC f16 transpose (blocks 0..2047)
//           + weight packing / bias27 (blocks 2048..2263)
// ---------------------------------------------------------------------------
__global__ __launch_bounds__(256) void prep_k(const float* __restrict__ x,
                                              unsigned short* __restrict__ xt,
                                              const float* __restrict__ w,
                                              const float* __restrict__ w_off,
                                              const float* __restrict__ w_mod,
                                              const float* __restrict__ b_off,
                                              const float* __restrict__ b_mod,
                                              unsigned short* __restrict__ wpackM,
                                              unsigned short* __restrict__ wq,
                                              float* __restrict__ bias27) {
    __shared__ float tile[64][65];
    int blk = blockIdx.x;
    if (blk < 2048) {                              // ---- transpose ----
        int b    = blk >> 8;
        int pos0 = (blk & 255) << 6;
        int lane = threadIdx.x & 63;
        int g    = threadIdx.x >> 6;
        for (int c = g; c < 64; c += 4)
            tile[c][lane] = x[(((b << 6) + c) << 14) + pos0 + lane];
        __syncthreads();
        // vectorized: 2 entries/thread; entry = 8 channels (one dwordx4) of
        // one position. Wave writes 1KB contiguous per instr.
        #pragma unroll
        for (int ee = 0; ee < 2; ++ee) {
            int E  = (ee << 8) + threadIdx.x;      // 0..511
            int pr = E >> 3;                       // position 0..63
            int j  = E & 7;                        // channel chunk
            uint4 d;
            d.x = pack2h(tile[(j << 3) + 0][pr], tile[(j << 3) + 1][pr]);
            d.y = pack2h(tile[(j << 3) + 2][pr], tile[(j << 3) + 3][pr]);
            d.z = pack2h(tile[(j << 3) + 4][pr], tile[(j << 3) + 5][pr]);
            d.w = pack2h(tile[(j << 3) + 6][pr], tile[(j << 3) + 7][pr]);
            *(uint4*)&xt[((size_t)((b << 14) + pos0 + pr) << 6) + (j << 3)] = d;
        }
        return;
    }
    // ---- weight packing ----
    int t = (blk - 2048) * 256 + threadIdx.x;
    if (t < 64 * 576) {
        int o = t / 576, kk = t % 576;
        int k = kk >> 6, c = kk & 63;
        wpackM[t] = __half_as_ushort(__float2half_rn(w[(o * 64 + c) * 9 + k]));
        return;
    }
    t -= 64 * 576;
    if (t < 32 * 576) {
        int o = t / 576, kk = t % 576;
        int k = kk >> 6, c = kk & 63;
        float v = 0.f;
        if (o < 18)      v = w_off[(o * 64 + c) * 9 + k];
        else if (o < 27) v = w_mod[((o - 18) * 64 + c) * 9 + k];
        int s = o >> 4, r = o & 15;
        int chh = c >> 5, q = (c >> 3) & 3, j = c & 7;
        int dst = (((((k << 1) + chh) << 1) + s) << 9) + (q << 7) + (r << 3) + j;
        wq[dst] = __half_as_ushort(__float2half_rn(v));
        if (kk == 0) bias27[o] = (o < 18) ? b_off[o] : (o < 27 ? b_mod[o - 18] : 0.f);
    }
}

// ---------------------------------------------------------------------------
// Kernel 2: offset/mask conv (27 ch, padded to 32) — LDS-free implicit GEMM.
// Unchanged from R15.
// ---------------------------------------------------------------------------
__global__ __launch_bounds__(256) void conv27_k(const unsigned short* __restrict__ xt,
                                                const unsigned short* __restrict__ wq,
                                                const float* __restrict__ bias27,
                                                float* __restrict__ offP) {
    int blk   = blockIdx.x;                         // 1024 = 8 b * 128 patches
    int b     = blk >> 7;
    int patch = blk & 127;
    int m     = patch >> 1;                         // row pair
    int h     = patch & 1;                          // col half
    int tid   = threadIdx.x;
    int lane  = tid & 63, wv = tid >> 6;
    int r = lane & 15, q = lane >> 4;

    const unsigned short* xb = xt + ((size_t)b << 20);
    int rb  = (m << 1) - 1;                         // top source row of patch
    int cxb = (h << 6) + (wv << 4) + r - 1;         // per-lane source col base
    int chq = (q << 3);                             // lane channel sub-chunk

    floatx4 acc[4] = {};                            // [s*2 + tr]
    #pragma unroll
    for (int k = 0; k < 9; ++k) {
        int ki = k / 3, kj = k % 3;
        #pragma unroll
        for (int chh = 0; chh < 2; ++chh) {
            int abase = ((((k << 1) + chh) << 1) << 9) + (lane << 3);
            half8 a0 = *(const half8*)&wq[abase];           // s=0 block
            half8 a1 = *(const half8*)&wq[abase + 512];     // s=1 block
            #pragma unroll
            for (int tr = 0; tr < 2; ++tr) {
                int sy = rb + tr + ki;
                int sx = cxb + kj;
                half8 bf = {};
                if ((unsigned)sy < 128u && (unsigned)sx < 128u)
                    bf = *(const half8*)&xb[(size_t)(((sy << 7) + sx) << 6) + (chh << 5) + chq];
                acc[0 + tr] = __builtin_amdgcn_mfma_f32_16x16x32_f16(a0, bf, acc[0 + tr], 0, 0, 0);
                acc[2 + tr] = __builtin_amdgcn_mfma_f32_16x16x32_f16(a1, bf, acc[2 + tr], 0, 0, 0);
            }
        }
    }

    #pragma unroll
    for (int s = 0; s < 2; ++s) {
        #pragma unroll
        for (int tr = 0; tr < 2; ++tr) {
            #pragma unroll
            for (int reg = 0; reg < 4; ++reg) {
                int oc = (s << 4) + (q << 2) + reg;
                if (oc >= 27) continue;
                int pos = (((m << 1) + tr) << 7) + (h << 6) + (wv << 4) + r;
                float v = acc[(s << 1) + tr][reg] + bias27[oc];
                int kk, comp;
                if (oc < 18) { kk = oc >> 1; comp = oc & 1; }
                else         { kk = oc - 18; comp = 2; v = 2.f / (1.f + __expf(-v)); }
                offP[(size_t)(((b * 9 + kk) * 3 + comp) << 14) + pos] = v;
            }
        }
    }
}

// ---------------------------------------------------------------------------
// Kernel 3: main deformable conv — R12 two-tap pipeline; samp in flat
// read-contiguous layout: half (pos p, h) at
//   [p>>4]*1024 + (h>>5)*512 + ((h>>3)&3)*128 + (p&15)*8 + (h&7)
// B-frag read (nt,ch): offset = nt*1024 + ch*512 + lane*8 -> 1KB contiguous.
// blendStore write: one contiguous b128 per i. LDS 30208 B.
// ---------------------------------------------------------------------------
__global__ __launch_bounds__(256, 3) void deform_main_k(const unsigned short* __restrict__ xt,
                                                        const unsigned short* __restrict__ wpackM,
                                                        const float* __restrict__ offP,
                                                        const float* __restrict__ bias,
                                                        float* __restrict__ out) {
    __shared__ ushort4 pOff[576];                   // 4608 B  corner pos-indices
    __shared__ uint4   pW[576];                     // 9216 B  4x f16x2 weights
    __shared__ unsigned short samp[2][4096];        // 16384 B B-tile (double buf)
    int blk  = blockIdx.x;                          // 2048 = 8 b * 256
    int b    = blk >> 8;
    int pos0 = (blk & 255) << 6;
    int tid  = threadIdx.x;
    int lane = tid & 63, wv = tid >> 6;
    int r = lane & 15, q = lane >> 4;
    int pg = lane >> 3;                             // position subgroup 0..7
    int j8 = lane & 7;                              // channel chunk (8 f16 = 16B)

    const char* xbb = (const char*)(xt + ((size_t)b << 20));

    // ---- phase 0: params, one thread per (tap,pos) entry ----
    for (int e = tid; e < 576; e += 256) {
        int k = e >> 6, p = e & 63;
        int pos = pos0 + p;
        const float* offk = offP + ((size_t)((b * 9 + k) * 3) << 14);
        float dy = offk[pos];
        float dx = offk[16384 + pos];
        float m  = offk[32768 + pos];
        float py = (float)(pos >> 7) + (float)(k / 3 - 1) + dy;
        float px = (float)(pos & 127) + (float)(k % 3 - 1) + dx;
        float y0f = floorf(py), x0f = floorf(px);
        int y0 = (int)y0f, x0 = (int)x0f;
        float wy1 = py - y0f, wx1 = px - x0f;
        float wy0 = 1.f - wy1, wx0 = 1.f - wx1;
        bool vy0 = (y0 >= 0) && (y0 < 128);
        bool vy1 = (y0 >= -1) && (y0 < 127);
        bool vx0 = (x0 >= 0) && (x0 < 128);
        bool vx1 = (x0 >= -1) && (x0 < 127);
        float w00 = (vy0 && vx0) ? m * wy0 * wx0 : 0.f;
        float w01 = (vy0 && vx1) ? m * wy0 * wx1 : 0.f;
        float w10 = (vy1 && vx0) ? m * wy1 * wx0 : 0.f;
        float w11 = (vy1 && vx1) ? m * wy1 * wx1 : 0.f;
        int y0c = min(max(y0, 0), 127), y1c = min(max(y0 + 1, 0), 127);
        int x0c = min(max(x0, 0), 127), x1c = min(max(x0 + 1, 0), 127);
        ushort4 io;
        io.x = (unsigned short)((y0c << 7) + x0c);
        io.y = (unsigned short)((y0c << 7) + x1c);
        io.z = (unsigned short)((y1c << 7) + x0c);
        io.w = (unsigned short)((y1c << 7) + x1c);
        pOff[e] = io;
        union { uint4 u; __half2 h[4]; } pw;
        pw.h[0] = __float2half2_rn(w00);
        pw.h[1] = __float2half2_rn(w01);
        pw.h[2] = __float2half2_rn(w10);
        pw.h[3] = __float2half2_rn(w11);
        pW[e] = pw.u;
    }
    __syncthreads();                                // pOff/pW ready

    floatx4 acc[4] = {};
    const char* xp = xbb + (j8 << 4);               // per-lane channel-chunk base
    const unsigned short* wrow = wpackM + ((wv << 4) + r) * 576 + (q << 3);

    uint4   c00[2][2], c01[2][2], c10[2][2], c11[2][2];  // [set][i]
    uint4   cwS[2][2];                              // weights per set
    ushort4 nio[2];                                 // staged params (next issue)
    uint4   ncw[2];
    half8   afC[2], afN[2];                         // A-frags, current / next

    auto readParams = [&](int k) {
        #pragma unroll
        for (int i = 0; i < 2; ++i) {
            int e  = (k << 6) + (wv << 4) + (i << 3) + pg;
            nio[i] = pOff[e];
            ncw[i] = pW[e];
        }
    };
    auto issueInto = [&](int s) {                   // s is compile-time at all call sites
        #pragma unroll
        for (int i = 0; i < 2; ++i) {
            cwS[s][i] = ncw[i];
            c00[s][i] = *(const uint4*)(xp + ((int)nio[i].x << 7));
            c01[s][i] = *(const uint4*)(xp + ((int)nio[i].y << 7));
            c10[s][i] = *(const uint4*)(xp + ((int)nio[i].z << 7));
            c11[s][i] = *(const uint4*)(xp + ((int)nio[i].w << 7));
        }
    };
    auto blendStore = [&](int s, int buf) {         // s, buf compile-time
        #pragma unroll
        for (int i = 0; i < 2; ++i) {
            union { uint4 u; __half2 h[4]; } W; W.u = cwS[s][i];
            uint4 o4;
            o4.x = blend2h(c00[s][i].x, c01[s][i].x, c10[s][i].x, c11[s][i].x, W.h);
            o4.y = blend2h(c00[s][i].y, c01[s][i].y, c10[s][i].y, c11[s][i].y, W.h);
            o4.z = blend2h(c00[s][i].z, c01[s][i].z, c10[s][i].z, c11[s][i].z, W.h);
            o4.w = blend2h(c00[s][i].w, c01[s][i].w, c10[s][i].w, c11[s][i].w, W.h);
            // half h=8*j8+j of pos p=(wv<<4)+(i<<3)+pg:
            //   off = wv*1024 + (j8>>2)*512 + (j8&3)*128 + (i*8+pg)*8
            *(uint4*)&samp[buf][(wv << 10) + ((j8 >> 2) << 9) + ((j8 & 3) << 7)
                               + (((i << 3) + pg) << 3)] = o4;
        }
    };

    // LDS-only barrier: commit this wave's ds_writes (lgkmcnt), then barrier.
    auto ldsBarrier = [&]() {
        asm volatile("s_waitcnt lgkmcnt(0)\n\ts_barrier" ::: "memory");
    };

    // prologue: taps 0 and 1 into the pipe; params(2) staged
    readParams(0); issueInto(0);
    readParams(1); issueInto(1);
    afC[0] = *(const half8*)&wrow[0];
    afC[1] = *(const half8*)&wrow[32];
    blendStore(0, 0);                               // blend tap0 -> samp[0]
    readParams(2);

    #pragma unroll
    for (int k = 0; k < 9; ++k) {
        if (k <= 6) issueInto(k & 1);               // corners for tap k+2
        if (k < 8) {
            afN[0] = *(const half8*)&wrow[((k + 1) << 6)];
            afN[1] = *(const half8*)&wrow[((k + 1) << 6) + 32];
        }
        ldsBarrier();                               // samp[k&1] complete block-wide
        #pragma unroll
        for (int ch = 0; ch < 2; ++ch) {
            #pragma unroll
            for (int nt = 0; nt < 4; ++nt) {
                // contiguous 1KB read: off = nt*1024 + ch*512 + lane*8
                half8 bfrag = *(const half8*)&samp[k & 1][(nt << 10) + (ch << 9) + (lane << 3)];
                acc[nt] = __builtin_amdgcn_mfma_f32_16x16x32_f16(afC[ch], bfrag, acc[nt], 0, 0, 0);
            }
        }
        if (k < 8) {
            blendStore((k + 1) & 1, (k + 1) & 1);   // corners issued at body k-1
            if (k <= 5) readParams(k + 3);          // params for issue at body k+1
            afC[0] = afN[0];
            afC[1] = afN[1];
        }
    }

    #pragma unroll
    for (int nt = 0; nt < 4; ++nt) {
        #pragma unroll
        for (int reg = 0; reg < 4; ++reg) {
            int oc  = (wv << 4) + (q << 2) + reg;
            int pos = pos0 + (nt << 4) + r;
            float v = acc[nt][reg] + bias[oc];
            out[(size_t)(((b << 6) + oc) << 14) + pos] = fmaxf(v, 0.f);
        }
    }
}

// ---------------------------------------------------------------------------
extern "C" void kernel_launch(void* const* d_in, const int* in_sizes, int n_in,
                              void* d_out, int out_size, void* d_ws, size_t ws_size,
                              hipStream_t stream) {
    const float* data  = (const float*)d_in[0];
    const float* w     = (const float*)d_in[1];
    const float* bias  = (const float*)d_in[2];
    const float* w_off = (const float*)d_in[3];
    const float* b_off = (const float*)d_in[4];
    const float* w_mod = (const float*)d_in[5];
    const float* b_mod = (const float*)d_in[6];
    float* out = (float*)d_out;

    char* ws = (char*)d_ws;
    unsigned short* dataT   = (unsigned short*)(ws + OFF_DATAT);
    float*          offP    = (float*)(ws + OFF_OFFP);
    unsigned short* wpackM  = (unsigned short*)(ws + OFF_WM);
    unsigned short* wq      = (unsigned short*)(ws + OFF_W27);
    float*          bias27  = (float*)(ws + OFF_B27);

    prep_k<<<2264, 256, 0, stream>>>(data, dataT, w, w_off, w_mod,
                                     b_off, b_mod, wpackM, wq, bias27);
    conv27_k<<<1024, 256, 0, stream>>>(dataT, wq, bias27, offP);
    deform_main_k<<<2048, 256, 0, stream>>>(dataT, wpackM, offP, bias, out);
}

// Round 9
// 162.767 us; speedup vs baseline: 2.6616x; 1.0130x over previous
//
#include <hip/hip_runtime.h>
#include <hip/hip_fp16.h>
#include <cstdint>

// ---------------------------------------------------------------------------
// SingleDeformConv on MI355X (gfx950)
// data (8,64,128,128) f32; w (64,64,3,3); b (64); w_off (18,64,3,3); b_off(18);
// w_mod (9,64,3,3); b_mod (9).  out = relu(deform_conv(...)) (8,64,128,128) f32
//
// R19 -> R20: revert deform/prep to R15-exact (R19's flat samp layout was an
// 8-way WRITE conflict: +256B stride = bank stride 64 = 0 mod 32; conflicts
// 2.36M -> 8.26M, deform +2us. deform 45.3us now declared practical floor:
// 7 structural variants all >= it). Single lever: conv27 block granularity
// 2-row -> 1-row patches (grid 1024 -> 2048, 4 -> 8 blocks/CU, 36 -> 18
// scattered B-loads/wave). Mechanism: conv27's B-frags touch 16 distinct
// 128B lines/instr; at 4 blocks/CU that latency is poorly hidden. Doubling
// co-residency halves per-CU exposure if latency-bound. If total stays ~160,
// conv27+gap was gap-dominated -> next round states the ceiling arithmetic.
// ---------------------------------------------------------------------------

typedef _Float16 half8 __attribute__((ext_vector_type(8)));
typedef __attribute__((ext_vector_type(4))) float floatx4;

// pack two floats -> f16x2 dword (RNE)
__device__ __forceinline__ unsigned int pack2h(float lo, float hi) {
    __half2 h = __floats2half2_rn(lo, hi);
    union { __half2 h; unsigned int u; } cv; cv.h = h;
    return cv.u;
}
// blend one f16x2 dword from 4 corners with broadcast __half2 weights
__device__ __forceinline__ unsigned int blend2h(unsigned int a, unsigned int b,
                                                unsigned int c, unsigned int d,
                                                const __half2* w) {
    union { unsigned int u; __half2 h; } A, B, C, D, O;
    A.u = a; B.u = b; C.u = c; D.u = d;
    __half2 s = __hmul2(A.h, w[0]);
    s = __hfma2(B.h, w[1], s);
    s = __hfma2(C.h, w[2], s);
    s = __hfma2(D.h, w[3], s);
    O.h = s;
    return O.u;
}

// Workspace layout (bytes) — R15 layout
#define OFF_DATAT 0u               // [8][16384][64] f16   = 16777216 B
#define OFF_OFFP  16777216u        // [8][9][3][16384] f32 = 14155776 B (dy,dx,mask)
#define OFF_WM    30932992u        // [64][576] f16        = 73728 B
#define OFF_W27   31006720u        // wq[9][2][2][4][16][8] f16 = 36864 B
#define OFF_B27   31043584u        // [32] f32             = 128 B
// total 31043712 B

// ---------------------------------------------------------------------------
// Kernel 1: prep = NCHW f32 -> NHWC f16 transpose (blocks 0..2047)
//           + weight packing / bias27 (blocks 2048..2263)   [R15-exact]
// ---------------------------------------------------------------------------
__global__ __launch_bounds__(256) void prep_k(const float* __restrict__ x,
                                              unsigned short* __restrict__ xt,
                                              const float* __restrict__ w,
                                              const float* __restrict__ w_off,
                                              const float* __restrict__ w_mod,
                                              const float* __restrict__ b_off,
                                              const float* __restrict__ b_mod,
                                              unsigned short* __restrict__ wpackM,
                                              unsigned short* __restrict__ wq,
                                              float* __restrict__ bias27) {
    __shared__ float tile[64][65];
    int blk = blockIdx.x;
    if (blk < 2048) {                              // ---- transpose ----
        int b    = blk >> 8;
        int pos0 = (blk & 255) << 6;
        int lane = threadIdx.x & 63;
        int g    = threadIdx.x >> 6;
        for (int c = g; c < 64; c += 4)
            tile[c][lane] = x[(((b << 6) + c) << 14) + pos0 + lane];
        __syncthreads();
        int c2 = lane & 31;
        for (int i = g; i < 32; i += 4) {
            int pr = (i << 1) + (lane >> 5);
            unsigned int d = pack2h(tile[c2 << 1][pr], tile[(c2 << 1) + 1][pr]);
            *(unsigned int*)&xt[((size_t)((b << 14) + pos0 + pr) << 6) + (c2 << 1)] = d;
        }
        return;
    }
    // ---- weight packing ----
    int t = (blk - 2048) * 256 + threadIdx.x;
    if (t < 64 * 576) {
        int o = t / 576, kk = t % 576;
        int k = kk >> 6, c = kk & 63;
        wpackM[t] = __half_as_ushort(__float2half_rn(w[(o * 64 + c) * 9 + k]));
        return;
    }
    t -= 64 * 576;
    if (t < 32 * 576) {
        int o = t / 576, kk = t % 576;
        int k = kk >> 6, c = kk & 63;
        float v = 0.f;
        if (o < 18)      v = w_off[(o * 64 + c) * 9 + k];
        else if (o < 27) v = w_mod[((o - 18) * 64 + c) * 9 + k];
        int s = o >> 4, r = o & 15;
        int chh = c >> 5, q = (c >> 3) & 3, j = c & 7;
        int dst = (((((k << 1) + chh) << 1) + s) << 9) + (q << 7) + (r << 3) + j;
        wq[dst] = __half_as_ushort(__float2half_rn(v));
        if (kk == 0) bias27[o] = (o < 18) ? b_off[o] : (o < 27 ? b_mod[o - 18] : 0.f);
    }
}

// ---------------------------------------------------------------------------
// Kernel 2: offset/mask conv (27 ch, padded to 32) — LDS-free implicit GEMM.
// 1-ROW patches: 2048 blocks = 8 b * 256 (128 rows x 2 col-halves).
// Per wave: 18 scattered B-loads (was 36), 8 blocks/CU (was 4).
// ---------------------------------------------------------------------------
__global__ __launch_bounds__(256) void conv27_k(const unsigned short* __restrict__ xt,
                                                const unsigned short* __restrict__ wq,
                                                const float* __restrict__ bias27,
                                                float* __restrict__ offP) {
    int blk   = blockIdx.x;                         // 2048 = 8 b * 256 patches
    int b     = blk >> 8;
    int patch = blk & 255;
    int row   = patch >> 1;                         // output row 0..127
    int h     = patch & 1;                          // col half
    int tid   = threadIdx.x;
    int lane  = tid & 63, wv = tid >> 6;
    int r = lane & 15, q = lane >> 4;

    const unsigned short* xb = xt + ((size_t)b << 20);
    int rb  = row - 1;                              // top source row
    int cxb = (h << 6) + (wv << 4) + r - 1;         // per-lane source col base
    int chq = (q << 3);                             // lane channel sub-chunk

    floatx4 acc[2] = {};                            // [s]
    #pragma unroll
    for (int k = 0; k < 9; ++k) {
        int ki = k / 3, kj = k % 3;
        #pragma unroll
        for (int chh = 0; chh < 2; ++chh) {
            int abase = ((((k << 1) + chh) << 1) << 9) + (lane << 3);
            half8 a0 = *(const half8*)&wq[abase];           // s=0 block
            half8 a1 = *(const half8*)&wq[abase + 512];     // s=1 block
            int sy = rb + ki;
            int sx = cxb + kj;
            half8 bf = {};
            if ((unsigned)sy < 128u && (unsigned)sx < 128u)
                bf = *(const half8*)&xb[(size_t)(((sy << 7) + sx) << 6) + (chh << 5) + chq];
            acc[0] = __builtin_amdgcn_mfma_f32_16x16x32_f16(a0, bf, acc[0], 0, 0, 0);
            acc[1] = __builtin_amdgcn_mfma_f32_16x16x32_f16(a1, bf, acc[1], 0, 0, 0);
        }
    }

    #pragma unroll
    for (int s = 0; s < 2; ++s) {
        #pragma unroll
        for (int reg = 0; reg < 4; ++reg) {
            int oc = (s << 4) + (q << 2) + reg;
            if (oc >= 27) continue;
            int pos = (row << 7) + (h << 6) + (wv << 4) + r;
            float v = acc[s][reg] + bias27[oc];
            int kk, comp;
            if (oc < 18) { kk = oc >> 1; comp = oc & 1; }
            else         { kk = oc - 18; comp = 2; v = 2.f / (1.f + __expf(-v)); }
            offP[(size_t)(((b * 9 + kk) * 3 + comp) << 14) + pos] = v;
        }
    }
}

// ---------------------------------------------------------------------------
// Kernel 3: main deformable conv — R12/R15-exact two-tap pipelined datapath.
// ---------------------------------------------------------------------------
__global__ __launch_bounds__(256, 3) void deform_main_k(const unsigned short* __restrict__ xt,
                                                        const unsigned short* __restrict__ wpackM,
                                                        const float* __restrict__ offP,
                                                        const float* __restrict__ bias,
                                                        float* __restrict__ out) {
    __shared__ ushort4 pOff[576];                   // 4608 B  corner pos-indices
    __shared__ uint4   pW[576];                     // 9216 B  4x f16x2 weights
    __shared__ unsigned short samp[2][64][72];      // 18432 B B-tile (double buf)
    int blk  = blockIdx.x;                          // 2048 = 8 b * 256
    int b    = blk >> 8;
    int pos0 = (blk & 255) << 6;
    int tid  = threadIdx.x;
    int lane = tid & 63, wv = tid >> 6;
    int r = lane & 15, q = lane >> 4;
    int pg = lane >> 3;                             // position subgroup 0..7
    int j8 = lane & 7;                              // channel chunk (8 f16 = 16B)

    const char* xbb = (const char*)(xt + ((size_t)b << 20));

    // ---- phase 0: params, one thread per (tap,pos) entry ----
    for (int e = tid; e < 576; e += 256) {
        int k = e >> 6, p = e & 63;
        int pos = pos0 + p;
        const float* offk = offP + ((size_t)((b * 9 + k) * 3) << 14);
        float dy = offk[pos];
        float dx = offk[16384 + pos];
        float m  = offk[32768 + pos];
        float py = (float)(pos >> 7) + (float)(k / 3 - 1) + dy;
        float px = (float)(pos & 127) + (float)(k % 3 - 1) + dx;
        float y0f = floorf(py), x0f = floorf(px);
        int y0 = (int)y0f, x0 = (int)x0f;
        float wy1 = py - y0f, wx1 = px - x0f;
        float wy0 = 1.f - wy1, wx0 = 1.f - wx1;
        bool vy0 = (y0 >= 0) && (y0 < 128);
        bool vy1 = (y0 >= -1) && (y0 < 127);
        bool vx0 = (x0 >= 0) && (x0 < 128);
        bool vx1 = (x0 >= -1) && (x0 < 127);
        float w00 = (vy0 && vx0) ? m * wy0 * wx0 : 0.f;
        float w01 = (vy0 && vx1) ? m * wy0 * wx1 : 0.f;
        float w10 = (vy1 && vx0) ? m * wy1 * wx0 : 0.f;
        float w11 = (vy1 && vx1) ? m * wy1 * wx1 : 0.f;
        int y0c = min(max(y0, 0), 127), y1c = min(max(y0 + 1, 0), 127);
        int x0c = min(max(x0, 0), 127), x1c = min(max(x0 + 1, 0), 127);
        ushort4 io;
        io.x = (unsigned short)((y0c << 7) + x0c);
        io.y = (unsigned short)((y0c << 7) + x1c);
        io.z = (unsigned short)((y1c << 7) + x0c);
        io.w = (unsigned short)((y1c << 7) + x1c);
        pOff[e] = io;
        union { uint4 u; __half2 h[4]; } pw;
        pw.h[0] = __float2half2_rn(w00);
        pw.h[1] = __float2half2_rn(w01);
        pw.h[2] = __float2half2_rn(w10);
        pw.h[3] = __float2half2_rn(w11);
        pW[e] = pw.u;
    }
    __syncthreads();                                // pOff/pW ready

    floatx4 acc[4] = {};
    const char* xp = xbb + (j8 << 4);               // per-lane channel-chunk base
    const unsigned short* wrow = wpackM + ((wv << 4) + r) * 576 + (q << 3);

    uint4   c00[2][2], c01[2][2], c10[2][2], c11[2][2];  // [set][i]
    uint4   cwS[2][2];                              // weights per set
    ushort4 nio[2];                                 // staged params (next issue)
    uint4   ncw[2];
    half8   afC[2], afN[2];                         // A-frags, current / next

    auto readParams = [&](int k) {
        #pragma unroll
        for (int i = 0; i < 2; ++i) {
            int e  = (k << 6) + (wv << 4) + (i << 3) + pg;
            nio[i] = pOff[e];
            ncw[i] = pW[e];
        }
    };
    auto issueInto = [&](int s) {                   // s is compile-time at all call sites
        #pragma unroll
        for (int i = 0; i < 2; ++i) {
            cwS[s][i] = ncw[i];
            c00[s][i] = *(const uint4*)(xp + ((int)nio[i].x << 7));
            c01[s][i] = *(const uint4*)(xp + ((int)nio[i].y << 7));
            c10[s][i] = *(const uint4*)(xp + ((int)nio[i].z << 7));
            c11[s][i] = *(const uint4*)(xp + ((int)nio[i].w << 7));
        }
    };
    auto blendStore = [&](int s, int buf) {         // s, buf compile-time
        #pragma unroll
        for (int i = 0; i < 2; ++i) {
            int p = (wv << 4) + (i << 3) + pg;
            union { uint4 u; __half2 h[4]; } W; W.u = cwS[s][i];
            uint4 o4;
            o4.x = blend2h(c00[s][i].x, c01[s][i].x, c10[s][i].x, c11[s][i].x, W.h);
            o4.y = blend2h(c00[s][i].y, c01[s][i].y, c10[s][i].y, c11[s][i].y, W.h);
            o4.z = blend2h(c00[s][i].z, c01[s][i].z, c10[s][i].z, c11[s][i].z, W.h);
            o4.w = blend2h(c00[s][i].w, c01[s][i].w, c10[s][i].w, c11[s][i].w, W.h);
            *(uint4*)&samp[buf][p][j8 << 3] = o4;
        }
    };

    // LDS-only barrier: commit this wave's ds_writes (lgkmcnt), then barrier.
    auto ldsBarrier = [&]() {
        asm volatile("s_waitcnt lgkmcnt(0)\n\ts_barrier" ::: "memory");
    };

    // prologue: taps 0 and 1 into the pipe; params(2) staged
    readParams(0); issueInto(0);
    readParams(1); issueInto(1);
    afC[0] = *(const half8*)&wrow[0];
    afC[1] = *(const half8*)&wrow[32];
    blendStore(0, 0);                               // blend tap0 -> samp[0]
    readParams(2);

    #pragma unroll
    for (int k = 0; k < 9; ++k) {
        if (k <= 6) issueInto(k & 1);               // corners for tap k+2
        if (k < 8) {
            afN[0] = *(const half8*)&wrow[((k + 1) << 6)];
            afN[1] = *(const half8*)&wrow[((k + 1) << 6) + 32];
        }
        ldsBarrier();                               // samp[k&1] complete block-wide
        #pragma unroll
        for (int ch = 0; ch < 2; ++ch) {
            #pragma unroll
            for (int nt = 0; nt < 4; ++nt) {
                half8 bfrag = *(const half8*)&samp[k & 1][(nt << 4) + r][(ch << 5) + (q << 3)];
                acc[nt] = __builtin_amdgcn_mfma_f32_16x16x32_f16(afC[ch], bfrag, acc[nt], 0, 0, 0);
            }
        }
        if (k < 8) {
            blendStore((k + 1) & 1, (k + 1) & 1);   // corners issued at body k-1
            if (k <= 5) readParams(k + 3);          // params for issue at body k+1
            afC[0] = afN[0];
            afC[1] = afN[1];
        }
    }

    #pragma unroll
    for (int nt = 0; nt < 4; ++nt) {
        #pragma unroll
        for (int reg = 0; reg < 4; ++reg) {
            int oc  = (wv << 4) + (q << 2) + reg;
            int pos = pos0 + (nt << 4) + r;
            float v = acc[nt][reg] + bias[oc];
            out[(size_t)(((b << 6) + oc) << 14) + pos] = fmaxf(v, 0.f);
        }
    }
}

// ---------------------------------------------------------------------------
extern "C" void kernel_launch(void* const* d_in, const int* in_sizes, int n_in,
                              void* d_out, int out_size, void* d_ws, size_t ws_size,
                              hipStream_t stream) {
    const float* data  = (const float*)d_in[0];
    const float* w     = (const float*)d_in[1];
    const float* bias  = (const float*)d_in[2];
    const float* w_off = (const float*)d_in[3];
    const float* b_off = (const float*)d_in[4];
    const float* w_mod = (const float*)d_in[5];
    const float* b_mod = (const float*)d_in[6];
    float* out = (float*)d_out;

    char* ws = (char*)d_ws;
    unsigned short* dataT   = (unsigned short*)(ws + OFF_DATAT);
    float*          offP    = (float*)(ws + OFF_OFFP);
    unsigned short* wpackM  = (unsigned short*)(ws + OFF_WM);
    unsigned short* wq      = (unsigned short*)(ws + OFF_W27);
    float*          bias27  = (float*)(ws + OFF_B27);

    prep_k<<<2264, 256, 0, stream>>>(data, dataT, w, w_off, w_mod,
                                     b_off, b_mod, wpackM, wq, bias27);
    conv27_k<<<2048, 256, 0, stream>>>(dataT, wq, bias27, offP);
    deform_main_k<<<2048, 256, 0, stream>>>(dataT, wpackM, offP, bias, out);
}